// Round 15
// baseline (938.425 us; speedup 1.0000x reference)
//
#include <hip/hip_runtime.h>
#include <hip/hip_bf16.h>

// LSTM2: B=1024, T=1024, H=64. R15: R14's P/Q wave-specialized pipeline with
// the block barrier replaced by flag-based producer/consumer sync.
// R14 diagnosis: per-CU LDS pipe ~880 cyc/step of DS ops, and s_barrier
// phase-aligns all 8 waves' bursts (frag reads, scratch writes) so queueing
// delay lands on every chain. Fix: decouple.
//   pdone/qdone: monotonic LDS counters, +1 per wave per completed step
//   (release); consumers acquire-spin. P leads, Q trails (1..4 steps).
//   h1: depth-4 ring (P flow-controlled by qdone >= 4*(t-3));
//   h2/headl: parity (Q internally <1 step skew via qdone).
// P-wave t: [spin pdone>=4t; t>=4: spin qdone>=4(t-3)]
//   a1(t)=W1.h1[(t-1)&3]+x_t (8 MFMA) -> scr1 -> cell1 -> h1[t&3]; pdone++
// Q-wave s: [spin pdone>=4(s+1); s>=1: spin qdone>=4s]
//   finalize out(s-1) (w4); a2(s)=W2.h1[s&3]+W3.h2[(s-1)&1] (16 MFMA) ->
//   scr2 -> cell2 -> h2[s&1] + head partial -> headl[s&1]; qdone++
// R13 gate-interleaved A-frags (D regs = 4 gates of one unit) + XOR-swizzled
// direct f32x4 stores kept. Layouts (m89/m91/m120).

typedef _Float16 f16x8 __attribute__((ext_vector_type(8)));
typedef float    f32x4 __attribute__((ext_vector_type(4)));

namespace {
constexpr int Bb = 1024;
constexpr int Tt = 1024;
constexpr int NBat = 4;    // batches per block
constexpr int HSTR = 72;   // f16 stride per batch row of h
constexpr int XSTR = 1025; // f32 stride per batch row of x

__device__ __forceinline__ int srow(int row) {      // XOR bank swizzle (R11)
    return row ^ ((row >> 3) & 7);
}
__device__ __forceinline__ float sigm(float x) {
    float e = __builtin_amdgcn_exp2f(-1.4426950408889634f * x);
    return __builtin_amdgcn_rcpf(1.0f + e);
}
__device__ __forceinline__ float tanh_f(float x) {
    float e = __builtin_amdgcn_exp2f(-2.8853900817779268f * x);
    return __builtin_amdgcn_rcpf(1.0f + e) * 2.0f - 1.0f;
}
// Dtype sniff (proven R2-R14).
__device__ __forceinline__ bool detect_f32(const void* w) {
    const unsigned short* p = (const unsigned short*)w;
    int sane = 0;
    for (int i = 0; i < 64; ++i) {
        int e = (p[2 * i] >> 7) & 0xFF;
        if (e >= 107 && e <= 129) ++sane;
    }
    return sane < 32;
}
__device__ __forceinline__ float ld(const void* p, int i, bool f32) {
    return f32 ? ((const float*)p)[i]
               : __bfloat162float(((const __hip_bfloat16*)p)[i]);
}
__device__ __forceinline__ void st(void* p, int i, float v, bool f32) {
    if (f32) ((float*)p)[i] = v;
    else     ((__hip_bfloat16*)p)[i] = __float2bfloat16(v);
}
__device__ __forceinline__ void spin_ge(unsigned* f, unsigned need) {
    // fast path: one acquire load; miss path: sleep to keep LDS pipe clear
    while (__hip_atomic_load(f, __ATOMIC_ACQUIRE,
                             __HIP_MEMORY_SCOPE_WORKGROUP) < need)
        __builtin_amdgcn_s_sleep(1);
}
__device__ __forceinline__ void bump(unsigned* f) {
    __hip_atomic_fetch_add(f, 1u, __ATOMIC_RELEASE,
                           __HIP_MEMORY_SCOPE_WORKGROUP);
}
} // namespace

__global__ __launch_bounds__(512, 1) void lstm2_kernel(
    const void* __restrict__ x,      // [B, T]
    const void* __restrict__ w_ih1,  // [256, 1]
    const void* __restrict__ w_hh1,  // [256, 64]
    const void* __restrict__ b_ih1,  // [256]
    const void* __restrict__ b_hh1,  // [256]
    const void* __restrict__ w_ih2,  // [256, 64]
    const void* __restrict__ w_hh2,  // [256, 64]
    const void* __restrict__ b_ih2,  // [256]
    const void* __restrict__ b_hh2,  // [256]
    const void* __restrict__ w_lin,  // [1, 64]
    const void* __restrict__ b_lin,  // [1]
    void* __restrict__ out)          // [B, T]
{
    const int tid  = threadIdx.x;
    const int lane = tid & 63;
    const int w    = tid >> 6;       // wave 0..7
    const int gw   = w & 3;          // group-local wave -> unit group 16gw..
    const bool isP = w < 4;          // P: L1 fast loop; Q: L2 pipeline
    const int m    = lane & 15;      // MFMA col (batch; valid m<NBat)
    const int quad = lane >> 4;
    const int bb   = blockIdx.x * NBat;

    const bool f32 = detect_f32(w_hh1);

    __shared__ float                  xs[NBat * XSTR];
    __shared__ __align__(16) _Float16 h1buf[4][16 * HSTR];  // depth-4 ring
    __shared__ __align__(16) _Float16 h2buf[2][16 * HSTR];  // parity
    __shared__ __align__(16) float    scr1[4][64 * 4];      // P-wave scratch
    __shared__ __align__(16) float    scr2[4][64 * 4];      // Q-wave scratch
    __shared__ float                  headl[2][16];         // [parity][gw*4+b]
    __shared__ unsigned               pdone, qdone;

    // ---- stage x + zero h buffers + init flags ----
    for (int i = tid; i < NBat * 1024; i += 512)
        xs[(i >> 10) * XSTR + (i & 1023)] = ld(x, (bb + (i >> 10)) * Tt + (i & 1023), f32);
    for (int i = tid; i < 16 * HSTR; i += 512) {
        h1buf[0][i] = (_Float16)0; h1buf[1][i] = (_Float16)0;
        h1buf[2][i] = (_Float16)0; h1buf[3][i] = (_Float16)0;
        h2buf[0][i] = (_Float16)0; h2buf[1][i] = (_Float16)0;
    }
    if (tid == 0) { pdone = 0u; qdone = 0u; }

    // ---- A-fragments, gate-interleaved rows (R13) ----
    // tile row (lane&15) = 4*u_loc + g -> mem row 64*g + 16*gw + 4q + u_loc
    const int arow = lane & 15;
    const int g_ld = arow & 3;
    const int u_ld = arow >> 2;
    f16x8 wfA[4][2], wfB[4][2];   // P: wfA=W1 (wfB unused=0); Q: wfA=W2, wfB=W3
    {
        const void* MA = isP ? w_hh1 : w_ih2;
#pragma unroll
        for (int q = 0; q < 4; ++q) {
            const int row = 64 * g_ld + 16 * gw + 4 * q + u_ld;
#pragma unroll
            for (int s = 0; s < 2; ++s) {
                const int base = row * 64 + 32 * s + quad * 8;
                if (f32) {
                    const float* A = (const float*)MA;
                    const float* B = (const float*)w_hh2;
#pragma unroll
                    for (int j = 0; j < 8; ++j) {
                        wfA[q][s][j] = (_Float16)A[base + j];
                        wfB[q][s][j] = isP ? (_Float16)0.0f : (_Float16)B[base + j];
                    }
                } else {
                    const __hip_bfloat16* A = (const __hip_bfloat16*)MA;
                    const __hip_bfloat16* B = (const __hip_bfloat16*)w_hh2;
#pragma unroll
                    for (int j = 0; j < 8; ++j) {
                        wfA[q][s][j] = (_Float16)__bfloat162float(A[base + j]);
                        wfB[q][s][j] = isP ? (_Float16)0.0f
                                           : (_Float16)__bfloat162float(B[base + j]);
                    }
                }
            }
        }
    }
    // bias / wx per (tile q, gate r): D row r of tile q = gate r, unit 16gw+4q+quad
    f32x4 bv[4], wxv[4];
#pragma unroll
    for (int q = 0; q < 4; ++q)
#pragma unroll
        for (int r = 0; r < 4; ++r) {
            const int row = 64 * r + 16 * gw + 4 * q + quad;
            bv[q][r] = isP ? (ld(b_ih1, row, f32) + ld(b_hh1, row, f32))
                           : (ld(b_ih2, row, f32) + ld(b_hh2, row, f32));
            wxv[q][r] = isP ? ld(w_ih1, row, f32) : 0.0f;
        }
    // cell mapping: lane -> (batch cb, unit 16gw+uo)
    const int cb = lane >> 4;
    const int uo = lane & 15;
    const int cidx = srow(lane) * 4;
    const float wl_u = ld(w_lin, 16 * gw + uo, f32);
    const float blin = ld(b_lin, 0, f32);
    float cst = 0.0f;                 // c1 (P) or c2 (Q)
    __syncthreads();   // the ONLY block barrier: xs, zeroed bufs, flags

    if (isP) {
        // ================= P: layer-1 fast recurrence =================
        for (int t = 0; t < Tt; ++t) {
            if (t >= 1) spin_ge(&pdone, 4u * t);            // h1(t-1) ready
            if (t >= 4) spin_ge(&qdone, 4u * (t - 3));      // ring slot free
            f32x4 acc[4];
            const float xt = xs[(m & (NBat - 1)) * XSTR + t];
#pragma unroll
            for (int q = 0; q < 4; ++q)
#pragma unroll
                for (int r = 0; r < 4; ++r)
                    acc[q][r] = fmaf(xt, wxv[q][r], bv[q][r]);
            if (t > 0) {
                const _Float16* hp = h1buf[(t - 1) & 3] + m * HSTR;
                const f16x8 ba = *(const f16x8*)(hp + quad * 8);
                const f16x8 bb2 = *(const f16x8*)(hp + 32 + quad * 8);
#pragma unroll
                for (int q = 0; q < 4; ++q) {
                    acc[q] = __builtin_amdgcn_mfma_f32_16x16x32_f16(wfA[q][0], ba, acc[q], 0, 0, 0);
                    acc[q] = __builtin_amdgcn_mfma_f32_16x16x32_f16(wfA[q][1], bb2, acc[q], 0, 0, 0);
                }
            }
            if (m < NBat)
#pragma unroll
                for (int q = 0; q < 4; ++q)
                    *(f32x4*)&scr1[gw][srow(m * 16 + q * 4 + quad) * 4] = acc[q];
            const f32x4 g = *(const f32x4*)&scr1[gw][cidx];   // i,f,g,o
            float ig = sigm(g[0]), fg = sigm(g[1]);
            float gg = tanh_f(g[2]), og = sigm(g[3]);
            cst = fmaf(fg, cst, ig * gg);
            h1buf[t & 3][cb * HSTR + 16 * gw + uo] = (_Float16)(og * tanh_f(cst));
            if (lane == 0) bump(&pdone);
        }
    } else {
        // ================= Q: layer-2 pipeline (trails P) =================
        for (int s = 0; s < Tt; ++s) {
            spin_ge(&pdone, 4u * (s + 1));                  // h1(s) ready
            if (s >= 1) spin_ge(&qdone, 4u * s);            // h2(s-1), headl
            if (s >= 1 && w == 4 && lane < NBat) {          // out(s-1)
                float sum = blin;
#pragma unroll
                for (int k = 0; k < 4; ++k) sum += headl[(s - 1) & 1][k * 4 + lane];
                st(out, (bb + lane) * Tt + (s - 1), sum, f32);
            }
            const _Float16* h1p = h1buf[s & 3] + m * HSTR;
            const _Float16* h2p = h2buf[(s - 1) & 1] + m * HSTR;  // zeroed at s=0
            const f16x8 b1a = *(const f16x8*)(h1p + quad * 8);
            const f16x8 b1b = *(const f16x8*)(h1p + 32 + quad * 8);
            const f16x8 b2a = *(const f16x8*)(h2p + quad * 8);
            const f16x8 b2b = *(const f16x8*)(h2p + 32 + quad * 8);
            f32x4 acc[4];
#pragma unroll
            for (int q = 0; q < 4; ++q) {
                f32x4 p = __builtin_amdgcn_mfma_f32_16x16x32_f16(wfA[q][0], b1a, bv[q], 0, 0, 0);
                p = __builtin_amdgcn_mfma_f32_16x16x32_f16(wfA[q][1], b1b, p, 0, 0, 0);
                p = __builtin_amdgcn_mfma_f32_16x16x32_f16(wfB[q][0], b2a, p, 0, 0, 0);
                acc[q] = __builtin_amdgcn_mfma_f32_16x16x32_f16(wfB[q][1], b2b, p, 0, 0, 0);
            }
            if (m < NBat)
#pragma unroll
                for (int q = 0; q < 4; ++q)
                    *(f32x4*)&scr2[gw][srow(m * 16 + q * 4 + quad) * 4] = acc[q];
            const f32x4 g = *(const f32x4*)&scr2[gw][cidx];
            float ig = sigm(g[0]), fg = sigm(g[1]);
            float gg = tanh_f(g[2]), og = sigm(g[3]);
            cst = fmaf(fg, cst, ig * gg);
            float h = og * tanh_f(cst);
            h2buf[s & 1][cb * HSTR + 16 * gw + uo] = (_Float16)h;
            float p = h * wl_u;                   // reduce over uo (same cb)
            p += __shfl_xor(p, 1); p += __shfl_xor(p, 2);
            p += __shfl_xor(p, 4); p += __shfl_xor(p, 8);
            if (uo == 0) headl[s & 1][gw * 4 + cb] = p;
            if (lane == 0) bump(&qdone);
        }
        // final output: needs ALL Q waves' partials of step Tt-1
        if (w == 4) {
            spin_ge(&qdone, 4u * Tt);
            if (lane < NBat) {
                float sum = blin;
#pragma unroll
                for (int k = 0; k < 4; ++k) sum += headl[(Tt - 1) & 1][k * 4 + lane];
                st(out, (bb + lane) * Tt + (Tt - 1), sum, f32);
            }
        }
    }
}

extern "C" void kernel_launch(void* const* d_in, const int* in_sizes, int n_in,
                              void* d_out, int out_size, void* d_ws, size_t ws_size,
                              hipStream_t stream)
{
    (void)in_sizes; (void)n_in; (void)out_size; (void)d_ws; (void)ws_size;
    lstm2_kernel<<<dim3(Bb / NBat), dim3(512), 0, stream>>>(
        d_in[0], d_in[1], d_in[2], d_in[3], d_in[4], d_in[5],
        d_in[6], d_in[7], d_in[8], d_in[9], d_in[10], d_out);
}

// Round 16
// 789.384 us; speedup vs baseline: 1.1888x; 1.1888x over previous
//
#include <hip/hip_runtime.h>
#include <hip/hip_bf16.h>

// LSTM2: B=1024, T=1024, H=64. R16: R14 (best, 826us) + two isolated trims.
//  (a) out stores buffered in LDS (outbuf[4][1024], 16KB), flushed once after
//      the loop -> no global store inside the loop -> the s_waitcnt vmcnt(0)
//      emitted before every s_barrier no longer waits on store retirement.
//  (b) Q's a2: two independent 2-deep MFMA chains + vector add (was 4-deep
//      dependent chain; dep-latency >> issue rate, and Q's chain is the wall).
// Structure otherwise identical to R14: 256 blocks (4 batches) x 8 waves,
// P-waves 0-3 run L1 recurrence at interval t, Q-waves 4-7 run L2 one step
// behind; ONE block barrier per interval. Parity audit: h1 W:t&1 R:(t-1)&1;
// h2 W:(t-1)&1 R:t&1; headl W:(t-1)&1 R:t&1 -- write!=read parity, reuse
// separated by a barrier. scr1/scr2 own-wave (in-order DS). R13 gate-
// interleaved A-frags + XOR-swizzled direct f32x4 stores.
// Layouts (m89/m91/m120): A[m=lane&15][k=(lane>>4)*8+j],
// B[k=(lane>>4)*8+j][n=lane&15], C/D: row=(lane>>4)*4+reg, col=lane&15.

typedef _Float16 f16x8 __attribute__((ext_vector_type(8)));
typedef float    f32x4 __attribute__((ext_vector_type(4)));

namespace {
constexpr int Bb = 1024;
constexpr int Tt = 1024;
constexpr int NBat = 4;    // batches per block
constexpr int HSTR = 72;   // f16 stride per batch row of h
constexpr int XSTR = 1025; // f32 stride per batch row of x

__device__ __forceinline__ int srow(int row) {      // XOR bank swizzle (R11)
    return row ^ ((row >> 3) & 7);
}
__device__ __forceinline__ float sigm(float x) {
    float e = __builtin_amdgcn_exp2f(-1.4426950408889634f * x);
    return __builtin_amdgcn_rcpf(1.0f + e);
}
__device__ __forceinline__ float tanh_f(float x) {
    float e = __builtin_amdgcn_exp2f(-2.8853900817779268f * x);
    return __builtin_amdgcn_rcpf(1.0f + e) * 2.0f - 1.0f;
}
// Dtype sniff (proven R2-R15).
__device__ __forceinline__ bool detect_f32(const void* w) {
    const unsigned short* p = (const unsigned short*)w;
    int sane = 0;
    for (int i = 0; i < 64; ++i) {
        int e = (p[2 * i] >> 7) & 0xFF;
        if (e >= 107 && e <= 129) ++sane;
    }
    return sane < 32;
}
__device__ __forceinline__ float ld(const void* p, int i, bool f32) {
    return f32 ? ((const float*)p)[i]
               : __bfloat162float(((const __hip_bfloat16*)p)[i]);
}
__device__ __forceinline__ void st(void* p, int i, float v, bool f32) {
    if (f32) ((float*)p)[i] = v;
    else     ((__hip_bfloat16*)p)[i] = __float2bfloat16(v);
}
} // namespace

__global__ __launch_bounds__(512, 1) void lstm2_kernel(
    const void* __restrict__ x,      // [B, T]
    const void* __restrict__ w_ih1,  // [256, 1]
    const void* __restrict__ w_hh1,  // [256, 64]
    const void* __restrict__ b_ih1,  // [256]
    const void* __restrict__ b_hh1,  // [256]
    const void* __restrict__ w_ih2,  // [256, 64]
    const void* __restrict__ w_hh2,  // [256, 64]
    const void* __restrict__ b_ih2,  // [256]
    const void* __restrict__ b_hh2,  // [256]
    const void* __restrict__ w_lin,  // [1, 64]
    const void* __restrict__ b_lin,  // [1]
    void* __restrict__ out)          // [B, T]
{
    const int tid  = threadIdx.x;
    const int lane = tid & 63;
    const int w    = tid >> 6;       // wave 0..7
    const int gw   = w & 3;          // group-local wave -> unit group 16gw..
    const bool isP = w < 4;          // P: L1 fast loop; Q: L2 pipeline
    const int m    = lane & 15;      // MFMA col (batch; valid m<NBat)
    const int quad = lane >> 4;
    const int bb   = blockIdx.x * NBat;

    const bool f32 = detect_f32(w_hh1);

    __shared__ float                  xs[NBat * XSTR];
    __shared__ __align__(16) _Float16 h1buf[2][16 * HSTR];  // parity-buffered
    __shared__ __align__(16) _Float16 h2buf[2][16 * HSTR];
    __shared__ __align__(16) float    scr1[4][64 * 4];      // P-wave scratch
    __shared__ __align__(16) float    scr2[4][64 * 4];      // Q-wave scratch
    __shared__ float                  headl[2][16];         // [parity][gw*4+b]
    __shared__ float                  outbuf[NBat * Tt];    // staged outputs

    // ---- stage x + zero h buffers (rows >= NBat stay 0 forever) ----
    for (int i = tid; i < NBat * 1024; i += 512)
        xs[(i >> 10) * XSTR + (i & 1023)] = ld(x, (bb + (i >> 10)) * Tt + (i & 1023), f32);
    for (int i = tid; i < 16 * HSTR; i += 512) {
        h1buf[0][i] = (_Float16)0; h1buf[1][i] = (_Float16)0;
        h2buf[0][i] = (_Float16)0; h2buf[1][i] = (_Float16)0;
    }

    // ---- A-fragments, gate-interleaved rows (R13) ----
    // tile row (lane&15) = 4*u_loc + g -> mem row 64*g + 16*gw + 4q + u_loc
    const int arow = lane & 15;
    const int g_ld = arow & 3;
    const int u_ld = arow >> 2;
    f16x8 wfA[4][2], wfB[4][2];   // P: wfA=W1 (wfB zero); Q: wfA=W2, wfB=W3
    {
        const void* MA = isP ? w_hh1 : w_ih2;
#pragma unroll
        for (int q = 0; q < 4; ++q) {
            const int row = 64 * g_ld + 16 * gw + 4 * q + u_ld;
#pragma unroll
            for (int s = 0; s < 2; ++s) {
                const int base = row * 64 + 32 * s + quad * 8;
                if (f32) {
                    const float* A = (const float*)MA;
                    const float* B = (const float*)w_hh2;
#pragma unroll
                    for (int j = 0; j < 8; ++j) {
                        wfA[q][s][j] = (_Float16)A[base + j];
                        wfB[q][s][j] = isP ? (_Float16)0.0f : (_Float16)B[base + j];
                    }
                } else {
                    const __hip_bfloat16* A = (const __hip_bfloat16*)MA;
                    const __hip_bfloat16* B = (const __hip_bfloat16*)w_hh2;
#pragma unroll
                    for (int j = 0; j < 8; ++j) {
                        wfA[q][s][j] = (_Float16)__bfloat162float(A[base + j]);
                        wfB[q][s][j] = isP ? (_Float16)0.0f
                                           : (_Float16)__bfloat162float(B[base + j]);
                    }
                }
            }
        }
    }
    // bias / wx per (tile q, gate r): D row r of tile q = gate r, unit 16gw+4q+quad
    f32x4 bv[4], wxv[4];
#pragma unroll
    for (int q = 0; q < 4; ++q)
#pragma unroll
        for (int r = 0; r < 4; ++r) {
            const int row = 64 * r + 16 * gw + 4 * q + quad;
            bv[q][r] = isP ? (ld(b_ih1, row, f32) + ld(b_hh1, row, f32))
                           : (ld(b_ih2, row, f32) + ld(b_hh2, row, f32));
            wxv[q][r] = isP ? ld(w_ih1, row, f32) : 0.0f;
        }
    // cell mapping: lane -> (batch cb, unit 16gw+uo)
    const int cb = lane >> 4;
    const int uo = lane & 15;
    const int cidx = srow(lane) * 4;
    const float wl_u = ld(w_lin, 16 * gw + uo, f32);
    const float blin = ld(b_lin, 0, f32);
    float cst = 0.0f;                 // c1 (P) or c2 (Q)
    __syncthreads();   // xs + zeroed h bufs visible

    for (int t = 0; t <= Tt; ++t) {
        if (isP) {
            if (t < Tt) {
                // ---- a1(t) = W1.h1(t-1) + x_t*wx + b1 ----
                f32x4 acc[4];
                const float xt = xs[(m & (NBat - 1)) * XSTR + t];
#pragma unroll
                for (int q = 0; q < 4; ++q)
#pragma unroll
                    for (int r = 0; r < 4; ++r)
                        acc[q][r] = fmaf(xt, wxv[q][r], bv[q][r]);
                if (t > 0) {
                    const _Float16* hp = h1buf[(t - 1) & 1] + m * HSTR;
                    const f16x8 ba = *(const f16x8*)(hp + quad * 8);
                    const f16x8 bb2 = *(const f16x8*)(hp + 32 + quad * 8);
#pragma unroll
                    for (int q = 0; q < 4; ++q) {
                        acc[q] = __builtin_amdgcn_mfma_f32_16x16x32_f16(wfA[q][0], ba, acc[q], 0, 0, 0);
                        acc[q] = __builtin_amdgcn_mfma_f32_16x16x32_f16(wfA[q][1], bb2, acc[q], 0, 0, 0);
                    }
                }
                if (m < NBat)
#pragma unroll
                    for (int q = 0; q < 4; ++q)
                        *(f32x4*)&scr1[gw][srow(m * 16 + q * 4 + quad) * 4] = acc[q];
                // ---- cell1(t): 1 eval/lane ----
                const f32x4 g = *(const f32x4*)&scr1[gw][cidx];   // i,f,g,o
                float ig = sigm(g[0]), fg = sigm(g[1]);
                float gg = tanh_f(g[2]), og = sigm(g[3]);
                cst = fmaf(fg, cst, ig * gg);
                h1buf[t & 1][cb * HSTR + 16 * gw + uo] = (_Float16)(og * tanh_f(cst));
            }
        } else {
            if (t > 0) {
                // ---- finalize out(t-2) -> LDS outbuf (no global store) ----
                if (t > 1 && w == 4 && lane < NBat) {
                    float s = blin;
#pragma unroll
                    for (int k = 0; k < 4; ++k) s += headl[t & 1][k * 4 + lane];
                    outbuf[lane * Tt + (t - 2)] = s;
                }
                // ---- a2(t-1) = W2.h1(t-1) + W3.h2(t-2) + b2 ----
                const _Float16* h1p = h1buf[(t - 1) & 1] + m * HSTR;
                const _Float16* h2p = h2buf[t & 1] + m * HSTR;
                const f16x8 b1a = *(const f16x8*)(h1p + quad * 8);
                const f16x8 b1b = *(const f16x8*)(h1p + 32 + quad * 8);
                const f16x8 b2a = *(const f16x8*)(h2p + quad * 8);
                const f16x8 b2b = *(const f16x8*)(h2p + 32 + quad * 8);
                f32x4 acc[4];
#pragma unroll
                for (int q = 0; q < 4; ++q) {   // two independent 2-deep chains
                    f32x4 p2 = __builtin_amdgcn_mfma_f32_16x16x32_f16(wfA[q][0], b1a, bv[q], 0, 0, 0);
                    p2 = __builtin_amdgcn_mfma_f32_16x16x32_f16(wfA[q][1], b1b, p2, 0, 0, 0);
                    f32x4 p3 = __builtin_amdgcn_mfma_f32_16x16x32_f16(wfB[q][0], b2a, f32x4{0,0,0,0}, 0, 0, 0);
                    p3 = __builtin_amdgcn_mfma_f32_16x16x32_f16(wfB[q][1], b2b, p3, 0, 0, 0);
                    acc[q] = p2 + p3;
                }
                if (m < NBat)
#pragma unroll
                    for (int q = 0; q < 4; ++q)
                        *(f32x4*)&scr2[gw][srow(m * 16 + q * 4 + quad) * 4] = acc[q];
                // ---- cell2(t-1): 1 eval/lane + head partial ----
                const f32x4 g = *(const f32x4*)&scr2[gw][cidx];
                float ig = sigm(g[0]), fg = sigm(g[1]);
                float gg = tanh_f(g[2]), og = sigm(g[3]);
                cst = fmaf(fg, cst, ig * gg);
                float h = og * tanh_f(cst);
                h2buf[(t - 1) & 1][cb * HSTR + 16 * gw + uo] = (_Float16)h;
                float p = h * wl_u;               // reduce over uo (same cb)
                p += __shfl_xor(p, 1); p += __shfl_xor(p, 2);
                p += __shfl_xor(p, 4); p += __shfl_xor(p, 8);
                if (uo == 0) headl[(t - 1) & 1][gw * 4 + cb] = p;
            }
        }
        __syncthreads();   // interval barrier: h1(t), h2(t-1), headl(t-1) visible
    }

    // ---- final: out(Tt-1) partials -> outbuf ----
    if (w == 4 && lane < NBat) {
        float s = blin;
#pragma unroll
        for (int k = 0; k < 4; ++k) s += headl[(Tt - 1) & 1][k * 4 + lane];
        outbuf[lane * Tt + (Tt - 1)] = s;
    }
    __syncthreads();
    // ---- cooperative coalesced flush: LDS outbuf -> global out ----
    for (int i = tid; i < NBat * Tt; i += 512)
        st(out, (bb + (i >> 10)) * Tt + (i & 1023), outbuf[i], f32);
}

extern "C" void kernel_launch(void* const* d_in, const int* in_sizes, int n_in,
                              void* d_out, int out_size, void* d_ws, size_t ws_size,
                              hipStream_t stream)
{
    (void)in_sizes; (void)n_in; (void)out_size; (void)d_ws; (void)ws_size;
    lstm2_kernel<<<dim3(Bb / NBat), dim3(512), 0, stream>>>(
        d_in[0], d_in[1], d_in[2], d_in[3], d_in[4], d_in[5],
        d_in[6], d_in[7], d_in[8], d_in[9], d_in[10], d_out);
}